// Round 4
// baseline (9542.459 us; speedup 1.0000x reference)
//
#include <hip/hip_runtime.h>

// ---------------------------------------------------------------------------
// Bidirectional GRU (Keras v2, reset_after=True) + dense tanh head, MI355X.
// B=128, T=512, D=300, U=300, DENSE=100.
//
// k_scan grid = 8 groups (2 dir x 4 batch-chunks of 32 rows) x 5 col-chunks
// (60 hidden cols each) = 40 blocks, 256 thr (waves 0-1 rec, 2-3 x@W).
// Col-chunk layout (192 cols): 4 triplets m of [z16|r16|h16] tiles, so the
// operand-swapped MFMA (D[j'][hrow]) leaves z/r/h for the same (row,j) in the
// same lane -> fully in-register gates, u64-aligned h stores.
// K of U is slab-padded: 5 slabs x 64 (rows 60..63 of each slab zeroed) so
// peer h-slabs map to exactly 2 K-tiles.
// Exchange: per-block tag (relaxed agent store, own cacheline) posted after
// the end-of-step barrier; consumers poll 4 peer tags then load peer slabs
// straight into MFMA B-fragments via agent u64 loads. Own slab via LDS.
// h carry stays fp32 in registers (never re-quantized).
// ---------------------------------------------------------------------------

typedef float f32x4 __attribute__((ext_vector_type(4)));
typedef short short8 __attribute__((ext_vector_type(8)));
typedef unsigned short u16;
typedef unsigned int u32;
typedef unsigned long long u64;

#define MFMA16(a, b, c) __builtin_amdgcn_mfma_f32_16x16x32_bf16((a), (b), (c), 0, 0, 0)

__device__ __forceinline__ u16 f2bf(float f) {
  u32 u = __float_as_uint(f);
  u = u + 0x7FFFu + ((u >> 16) & 1u);   // RNE
  return (u16)(u >> 16);
}
__device__ __forceinline__ float bf2f(u16 h) {
  return __uint_as_float(((u32)h) << 16);
}
__device__ __forceinline__ float sigm(float x) { return 1.f / (1.f + __expf(-x)); }
__device__ __forceinline__ float tanhx(float x) { return 1.f - 2.f / (__expf(2.f * x) + 1.f); }

// ---------------- workspace layout (bytes) ----------------
#define OFF_WT       0ULL          // bf16 [2][5][192][320]    1228800
#define OFF_UT       1228800ULL    // bf16 [2][5][192][320]    1228800 (K slab-padded)
#define OFF_BX       2457600ULL    // f32  [2][5][192]         7680  (b0 + b1 for z,r)
#define OFF_BH       2465280ULL    // f32  [2][5][192]         7680  (b1 for h gate)
#define OFF_WDT      2472960ULL    // bf16 [112][640]          143360
#define OFF_BDP      2616320ULL    // f32  [112] pad           512
#define OFF_MASK     2616832ULL    // f32  [65536]             262144
#define OFF_HSTATE   2878976ULL    // bf16 [8][2][32][5][64]   327680
#define OFF_TAGS     3206656ULL    // u32  [8][5] spaced x32   5120
#define OFF_XBF      3211776ULL    // bf16 [65536][320]        41943040
#define OFF_HALL     45154816ULL   // bf16 [65536][600]        78643200
#define WS_NEED      123798016ULL  // ~118 MB (r3-proven size)

// ---------------------------------------------------------------------------
__global__ __launch_bounds__(256) void k_sentinel(float* __restrict__ out,
                                                  float code, int n) {
  int i = blockIdx.x * 256 + threadIdx.x;
  if (i < n) out[i] = code;
}

// ---------------------------------------------------------------------------
// k_prep: weight repack.
// Col mapping (per dir d, chunk cc, col c in 0..191):
//   tile=c/16, m=tile/3, g=tile%3, i=c%16, jl=m*16+i; valid jl<60
//   real col = g*300 + cc*60 + jl
// WT K: plain 0..299 pad 320. UT K: slab s=k/64, jj=k%64; real row s*60+jj,
// valid jj<60 (pad rows zero).
// ---------------------------------------------------------------------------
__global__ __launch_bounds__(256) void k_prep(
    const float* __restrict__ Wf, const float* __restrict__ Uf,
    const float* __restrict__ bfp, const float* __restrict__ Wb,
    const float* __restrict__ Ub, const float* __restrict__ bbp,
    const float* __restrict__ Wd, const float* __restrict__ bd,
    u16* __restrict__ WT, u16* __restrict__ UT,
    float* __restrict__ BX, float* __restrict__ BH,
    u16* __restrict__ WdT, float* __restrict__ bdp)
{
  const long long NWU = 2LL * 5 * 192 * 320;  // 614400
  const long long TOTAL = NWU * 2 + 1920 * 2 + 71680 + 112;
  for (long long i = (long long)blockIdx.x * 256 + threadIdx.x; i < TOTAL;
       i += 2048LL * 256) {
    long long r = i;
    if (r < NWU) {  // WT
      int d = (int)(r / 307200); int q = (int)(r % 307200);
      int c = q / 320, k = q % 320;
      int cc = c / 192, ccol = c % 192;
      int tile = ccol / 16, ii = ccol % 16;
      int m = tile / 3, g = tile % 3, jl = m * 16 + ii;
      float v = 0.f;
      if (k < 300 && jl < 60) {
        const float* W = d ? Wb : Wf;
        v = W[k * 900 + g * 300 + cc * 60 + jl];
      }
      WT[r] = f2bf(v);
      continue;
    }
    r -= NWU;
    if (r < NWU) {  // UT (slab-padded K)
      int d = (int)(r / 307200); int q = (int)(r % 307200);
      int c = q / 320, k = q % 320;
      int cc = c / 192, ccol = c % 192;
      int tile = ccol / 16, ii = ccol % 16;
      int m = tile / 3, g = tile % 3, jl = m * 16 + ii;
      int s = k / 64, jj = k % 64;
      float v = 0.f;
      if (jj < 60 && jl < 60) {
        const float* U = d ? Ub : Uf;
        v = U[(s * 60 + jj) * 900 + g * 300 + cc * 60 + jl];
      }
      UT[r] = f2bf(v);
      continue;
    }
    r -= NWU;
    if (r < 1920 * 2) {  // BX then BH
      int which = (int)(r / 1920); int rr = (int)(r % 1920);
      int d = rr / 960; int c = rr % 960;
      int cc = c / 192, ccol = c % 192;
      int tile = ccol / 16, ii = ccol % 16;
      int m = tile / 3, g = tile % 3, jl = m * 16 + ii;
      float v = 0.f;
      if (jl < 60) {
        const float* B = d ? bbp : bfp;
        int col = g * 300 + cc * 60 + jl;
        if (which == 0) v = B[col] + (g < 2 ? B[900 + col] : 0.f);
        else            v = (g == 2) ? B[900 + col] : 0.f;
      }
      if (which == 0) BX[rr] = v; else BH[rr] = v;
      continue;
    }
    r -= 1920 * 2;
    if (r < 71680) {  // WdT [112][640]
      int n = (int)(r / 640); int k = (int)(r % 640);
      float v = (n < 100 && k < 600) ? Wd[k * 100 + n] : 0.f;
      WdT[r] = f2bf(v);
      continue;
    }
    r -= 71680;
    if (r < 112) bdp[r] = (r < 100) ? bd[r] : 0.f;
  }
}

// ---------------------------------------------------------------------------
// k_xbf: x -> bf16 (K-padded 320) + mask. One wave per (b,t) row.
// ---------------------------------------------------------------------------
__global__ __launch_bounds__(256) void k_xbf(const float* __restrict__ x,
                                             u16* __restrict__ xbf,
                                             float* __restrict__ mask)
{
  int row = blockIdx.x * 4 + (threadIdx.x >> 6);
  int l = threadIdx.x & 63;
  const float* xr = x + (size_t)row * 300;
  u16* xo = xbf + (size_t)row * 320;
  int p = 0;
#pragma unroll
  for (int c = 0; c < 5; ++c) {
    int k = l + c * 64;
    float v = (k < 300) ? xr[k] : 0.f;
    p |= (v != 0.f);
    xo[k] = f2bf(v);
  }
  unsigned long long b = __ballot(p);
  if (l == 0) mask[row] = (b != 0ULL) ? 1.f : 0.f;
}

// ---------------------------------------------------------------------------
// k_scan
// LDS: Ufrag 122880 | xgS [32][204] f32 26112 | hOwn [32][72] u16 4608
//      = 153600 B
// ---------------------------------------------------------------------------
__global__ __launch_bounds__(256, 1) void k_scan(
    const u16* __restrict__ UTg, const u16* __restrict__ WTg,
    const float* __restrict__ BX, const float* __restrict__ BH,
    const u16* __restrict__ xbf, const float* __restrict__ mask,
    u16* __restrict__ h_state, u16* __restrict__ h_all, u32* __restrict__ tags)
{
  extern __shared__ char smem[];
  u16*   Ufrag = (u16*)smem;                 // 122880 B (120 frags x 1024 B)
  float* xgS   = (float*)(smem + 122880);    // 26112 B  [32][204]
  u16*   hOwn  = (u16*)(smem + 148992);      // 4608 B   [32][72]

  const int tid = threadIdx.x;
  const int l = tid & 63;
  const int w = tid >> 6;
  const bool isrec = (w < 2);
  const int rt = isrec ? w : (w - 2);
  const int lc15 = l & 15, lq = l >> 4;
  const int row_loc = rt * 16 + lc15;        // h-row / x-row within 32

  const int gb = blockIdx.x & 7;             // group = d*4+bc
  const int cc = blockIdx.x >> 3;            // col-chunk 0..4
  const int d = gb >> 2, bc = gb & 3;

  const size_t chunk = (size_t)(d * 5 + cc) * 192 * 320;
  const u16* UT = UTg + chunk;
  const u16* WT = WTg + chunk;

  // ---- stage U fragments (once): frag f = nt*10+kt, lane ll ----
  for (int u = tid; u < 7680; u += 256) {
    int f = u >> 6, ll = u & 63;
    int col = (f / 10) * 16 + (ll & 15);
    int k = (f % 10) * 32 + ((ll >> 4) << 3);
    *(uint4*)(Ufrag + (size_t)u * 8) = *(const uint4*)(UT + (size_t)col * 320 + k);
  }
  for (int u = tid; u < 1152; u += 256) ((u32*)hOwn)[u] = 0;

  // persistent per-lane constants
  f32x4 bx[12]; f32x4 brh[4];
  float hold[4][4];
  if (isrec) {
#pragma unroll
    for (int m = 0; m < 4; ++m)
      brh[m] = *(const f32x4*)(BH + d * 960 + cc * 192 + (3 * m + 2) * 16 + lq * 4);
#pragma unroll
    for (int m = 0; m < 4; ++m)
#pragma unroll
      for (int e = 0; e < 4; ++e) hold[m][e] = 0.f;
  } else {
#pragma unroll
    for (int nt = 0; nt < 12; ++nt)
      bx[nt] = *(const f32x4*)(BX + d * 960 + cc * 192 + nt * 16 + lq * 4);
  }

  const int growb = bc * 32 + row_loc;       // global batch row
  u32* tg = tags + gb * 5 * 32;              // tags spaced 128 B
  const u16* wb = WT + (size_t)lc15 * 320 + (lq << 3);

  __syncthreads();

  for (int t = 0; t < 512; ++t) {
    const int t_eff = d ? (511 - t) : t;
    const size_t ridx = (size_t)growb * 512 + t_eff;

    f32x4 racc[12];
    float mk = 1.f;

    if (!isrec) {
      // ================= x waves: xg(t) = x @ W + bx =================
      short8 xF[10];
      const u16* xr = xbf + ridx * 320 + (lq << 3);
#pragma unroll
      for (int kt = 0; kt < 10; ++kt) xF[kt] = *(const short8*)(xr + kt * 32);
#pragma unroll
      for (int nt = 0; nt < 12; ++nt) { f32x4 z = {0.f, 0.f, 0.f, 0.f}; racc[nt] = z; }
#pragma unroll
      for (int kt = 0; kt < 10; ++kt) {
#pragma unroll
        for (int nt = 0; nt < 12; ++nt) {
          short8 wf = *(const short8*)(wb + (size_t)nt * 5120 + kt * 32);
          racc[nt] = MFMA16(wf, xF[kt], racc[nt]);
        }
      }
#pragma unroll
      for (int nt = 0; nt < 12; ++nt) {
        f32x4 v = racc[nt] + bx[nt];
        *(f32x4*)(xgS + row_loc * 204 + nt * 16 + lq * 4) = v;
      }
    } else {
      // ================= rec waves: rec(t) = h(t) @ U =================
      mk = mask[ridx];
      if (t > 0) {
        u32 need = (u32)t;
        for (;;) {
          u32 mn = 0xffffffffu;
#pragma unroll
          for (int s = 0; s < 5; ++s) {
            if (s != cc) {
              u32 v = __hip_atomic_load(tg + s * 32, __ATOMIC_RELAXED,
                                        __HIP_MEMORY_SCOPE_AGENT);
              mn = v < mn ? v : mn;
            }
          }
          if (mn >= need) break;
          __builtin_amdgcn_s_sleep(1);
        }
        asm volatile("" ::: "memory");  // keep data loads below the poll
      }
      // B-fragments: h[row_loc][k] ; own slab via LDS, peers via agent u64
      short8 hf[10];
      {
        const int par = t & 1;
        const u64* hb = (const u64*)(h_state +
            (((size_t)(gb * 2 + par) * 32 + row_loc) * 5) * 64);
#pragma unroll
        for (int s = 0; s < 5; ++s) {
          if (s == cc) continue;
#pragma unroll
          for (int kt2 = 0; kt2 < 2; ++kt2) {
            const u64* p = hb + s * 16 + kt2 * 8 + lq * 2;
            union { u64 q[2]; short8 v; } uu;
            uu.q[0] = __hip_atomic_load(p, __ATOMIC_RELAXED, __HIP_MEMORY_SCOPE_AGENT);
            uu.q[1] = __hip_atomic_load(p + 1, __ATOMIC_RELAXED, __HIP_MEMORY_SCOPE_AGENT);
            hf[s * 2 + kt2] = uu.v;
          }
        }
#pragma unroll
        for (int kt2 = 0; kt2 < 2; ++kt2)
          hf[cc * 2 + kt2] =
              *(const short8*)(hOwn + row_loc * 72 + kt2 * 32 + (lq << 3));
      }
#pragma unroll
      for (int nt = 0; nt < 12; ++nt) { f32x4 z = {0.f, 0.f, 0.f, 0.f}; racc[nt] = z; }
#pragma unroll
      for (int kt = 0; kt < 10; ++kt) {
#pragma unroll
        for (int nt = 0; nt < 12; ++nt) {
          short8 uf = *(const short8*)(Ufrag + ((size_t)(nt * 10 + kt) * 64 + l) * 8);
          racc[nt] = MFMA16(uf, hf[kt], racc[nt]);
        }
      }
    }

    __syncthreads();  // xgS(t) ready; rec acc in regs

    if (isrec) {
      const float* xgr = xgS + row_loc * 204;
      const bool msk = (mk != 0.f);
#pragma unroll
      for (int m = 0; m < 4; ++m) {
        f32x4 xzv = *(const f32x4*)(xgr + (3 * m) * 16 + lq * 4);
        f32x4 xrv = *(const f32x4*)(xgr + (3 * m + 1) * 16 + lq * 4);
        f32x4 xhv = *(const f32x4*)(xgr + (3 * m + 2) * 16 + lq * 4);
        u16 hb16[4];
#pragma unroll
        for (int e = 0; e < 4; ++e) {
          float z = sigm(xzv[e] + racc[3 * m][e]);
          float r = sigm(xrv[e] + racc[3 * m + 1][e]);
          float hh = tanhx(xhv[e] + r * (racc[3 * m + 2][e] + brh[m][e]));
          float hn = z * hold[m][e] + (1.f - z) * hh;
          hn = msk ? hn : hold[m][e];
          hold[m][e] = hn;
          hb16[e] = f2bf(hn);
        }
        if (m < 3 || lq < 3) {   // j0..j0+3 < 60
          int j0 = m * 16 + lq * 4;
          u32 lo = (u32)hb16[0] | ((u32)hb16[1] << 16);
          u32 hi = (u32)hb16[2] | ((u32)hb16[3] << 16);
          u64 pk = (u64)lo | ((u64)hi << 32);
          // device-coherent slab store for peers
          u64* hp = (u64*)(h_state +
              ((((size_t)(gb * 2 + ((t + 1) & 1)) * 32 + row_loc) * 5 + cc) * 64 + j0));
          __hip_atomic_store(hp, pk, __ATOMIC_RELAXED, __HIP_MEMORY_SCOPE_AGENT);
          // output h (read by k_dense after kernel end)
          *(u64*)(h_all + ridx * 600 + d * 300 + cc * 60 + j0) = pk;
          // own slab for next step
          *(u64*)(hOwn + row_loc * 72 + j0) = pk;
        }
      }
    }

    __syncthreads();  // drains all stores (vmcnt 0 per wave) before tag
    if (tid == 0)
      __hip_atomic_store(tg + cc * 32, (u32)(t + 1), __ATOMIC_RELAXED,
                         __HIP_MEMORY_SCOPE_AGENT);
  }
}

// ---------------------------------------------------------------------------
// k_dense: out = tanh(h_all @ Wd + bd). M=64 tile, static LDS 22.5 KB.
// ---------------------------------------------------------------------------
__global__ __launch_bounds__(256) void k_dense(
    const u16* __restrict__ h_all, const u16* __restrict__ WdT,
    const float* __restrict__ bdp, float* __restrict__ out)
{
  __shared__ u16 Bf[7 * 2 * 64 * 8];  // 14336 B
  __shared__ char A[8192];
  const int tid = threadIdx.x;
  const int l = tid & 63;
  const int w = tid >> 6;
  const int lc15 = l & 15, lq = l >> 4;
  const int mblk = blockIdx.x;

  f32x4 acc[7];
#pragma unroll
  for (int i = 0; i < 7; ++i) { f32x4 z = {0.f, 0.f, 0.f, 0.f}; acc[i] = z; }

  for (int kc = 0; kc < 10; ++kc) {
    for (int u = tid; u < 512; u += 256) {
      int row = u >> 3, oct = u & 7;
      int k0 = kc * 64 + oct * 8;
      uint4 v = {0u, 0u, 0u, 0u};
      if (k0 <= 592)
        v = *(const uint4*)(h_all + (size_t)(mblk * 64 + row) * 600 + k0);
      *(uint4*)(A + row * 128 + ((oct * 16) ^ ((row & 7) << 4))) = v;
    }
    for (int u = tid; u < 896; u += 256) {
      int idx = u >> 6, ll = u & 63;
      int nt = idx >> 1, ktp = idx & 1;
      int kt = kc * 2 + ktp;
      uint4 v = {0u, 0u, 0u, 0u};
      if (kt < 19) {
        int col = nt * 16 + (ll & 15);
        int k = kt * 32 + ((ll >> 4) << 3);
        v = *(const uint4*)(WdT + (size_t)col * 640 + k);
      }
      *(uint4*)(Bf + (size_t)u * 8) = v;
    }
    __syncthreads();
    const int r = w * 16 + lc15;
    const int swA = (r & 7) << 4;
#pragma unroll
    for (int ktp = 0; ktp < 2; ++ktp) {
      if (kc * 2 + ktp < 19) {
        short8 aF = *(const short8*)(A + r * 128 + ((ktp * 64 + (lq << 4)) ^ swA));
#pragma unroll
        for (int nt = 0; nt < 7; ++nt) {
          short8 bF = *(const short8*)(Bf + ((size_t)((nt * 2 + ktp) * 64 + l)) * 8);
          acc[nt] = MFMA16(aF, bF, acc[nt]);
        }
      }
    }
    __syncthreads();
  }
#pragma unroll
  for (int nt = 0; nt < 7; ++nt) {
    int col = nt * 16 + lc15;
    if (col < 100) {
      float bb = bdp[col];
#pragma unroll
      for (int e = 0; e < 4; ++e) {
        int row = w * 16 + lq * 4 + e;
        out[(size_t)(mblk * 64 + row) * 100 + col] = tanhx(acc[nt][e] + bb);
      }
    }
  }
}

// ---------------------------------------------------------------------------
extern "C" void kernel_launch(void* const* d_in, const int* in_sizes, int n_in,
                              void* d_out, int out_size, void* d_ws, size_t ws_size,
                              hipStream_t stream)
{
  (void)in_sizes; (void)n_in;
  const float* x  = (const float*)d_in[0];
  const float* Wf = (const float*)d_in[1];
  const float* Uf = (const float*)d_in[2];
  const float* bf = (const float*)d_in[3];
  const float* Wb = (const float*)d_in[4];
  const float* Ub = (const float*)d_in[5];
  const float* bb = (const float*)d_in[6];
  const float* Wd = (const float*)d_in[7];
  const float* bd = (const float*)d_in[8];
  float* out = (float*)d_out;
  char* ws = (char*)d_ws;

  hipError_t e1 = hipFuncSetAttribute((const void*)k_scan,
      hipFuncAttributeMaxDynamicSharedMemorySize, 153600);

  if (ws_size < WS_NEED || e1 != hipSuccess) {
    float code = (float)(ws_size >> 20) + (e1 != hipSuccess ? 100000.f : 0.f);
    int n = out_size;
    hipLaunchKernelGGL(k_sentinel, dim3((n + 255) / 256), dim3(256), 0, stream,
                       out, code, n);
    return;
  }

  u16*   WT      = (u16*)(ws + OFF_WT);
  u16*   UT      = (u16*)(ws + OFF_UT);
  float* BX      = (float*)(ws + OFF_BX);
  float* BH      = (float*)(ws + OFF_BH);
  u16*   WdT     = (u16*)(ws + OFF_WDT);
  float* bdp     = (float*)(ws + OFF_BDP);
  float* mask    = (float*)(ws + OFF_MASK);
  u16*   h_state = (u16*)(ws + OFF_HSTATE);
  u32*   tags    = (u32*)(ws + OFF_TAGS);
  u16*   xbf     = (u16*)(ws + OFF_XBF);
  u16*   h_all   = (u16*)(ws + OFF_HALL);

  // zero h_state + tags (contiguous)
  hipMemsetAsync(ws + OFF_HSTATE, 0, 327680 + 5120, stream);

  hipLaunchKernelGGL(k_prep, dim3(2048), dim3(256), 0, stream,
                     Wf, Uf, bf, Wb, Ub, bb, Wd, bd, WT, UT, BX, BH, WdT, bdp);
  hipLaunchKernelGGL(k_xbf, dim3(16384), dim3(256), 0, stream, x, xbf, mask);
  hipLaunchKernelGGL(k_scan, dim3(40), dim3(256), 153600, stream,
                     UT, WT, BX, BH, xbf, mask, h_state, h_all, tags);
  hipLaunchKernelGGL(k_dense, dim3(1024), dim3(256), 0, stream,
                     h_all, WdT, bdp, out);
}

// Round 8
// 9294.975 us; speedup vs baseline: 1.0266x; 1.0266x over previous
//
#include <hip/hip_runtime.h>

// ---------------------------------------------------------------------------
// Bidirectional GRU (Keras v2, reset_after=True) + dense tanh head, MI355X.
// B=128, T=512, D=300, U=300, DENSE=100.
//
// k_scan grid = 8 groups (2 dir x 4 batch-chunks of 32 rows) x 5 col-chunks
// (60 hidden cols each) = 40 blocks, 256 thr (waves 0-1 rec, 2-3 x@W).
// r6 changes vs r4:
//  (A) tag posted with RELEASE (vmcnt drain + buffer_wbl2 -> h slab flushed
//      to L3 immediately); poll exits through one ACQUIRE load.
//  (B) WT stored FRAGMENT-MAJOR in global ([frag][lane][8]) so each x-wave
//      load is 1 KB contiguous (r4 scattered 64 cachelines/instr on the
//      critical path).
// h carry stays fp32 in registers (never re-quantized).
// ---------------------------------------------------------------------------

typedef float f32x4 __attribute__((ext_vector_type(4)));
typedef short short8 __attribute__((ext_vector_type(8)));
typedef unsigned short u16;
typedef unsigned int u32;
typedef unsigned long long u64;

#define MFMA16(a, b, c) __builtin_amdgcn_mfma_f32_16x16x32_bf16((a), (b), (c), 0, 0, 0)

__device__ __forceinline__ u16 f2bf(float f) {
  u32 u = __float_as_uint(f);
  u = u + 0x7FFFu + ((u >> 16) & 1u);   // RNE
  return (u16)(u >> 16);
}
__device__ __forceinline__ float bf2f(u16 h) {
  return __uint_as_float(((u32)h) << 16);
}
__device__ __forceinline__ float sigm(float x) { return 1.f / (1.f + __expf(-x)); }
__device__ __forceinline__ float tanhx(float x) { return 1.f - 2.f / (__expf(2.f * x) + 1.f); }

// ---------------- workspace layout (bytes) ----------------
#define OFF_WT       0ULL          // bf16 [2][5][120][64][8]  1228800 (fragment-major)
#define OFF_UT       1228800ULL    // bf16 [2][5][192][320]    1228800 (K slab-padded)
#define OFF_BX       2457600ULL    // f32  [2][5][192]         7680  (b0 + b1 for z,r)
#define OFF_BH       2465280ULL    // f32  [2][5][192]         7680  (b1 for h gate)
#define OFF_WDT      2472960ULL    // bf16 [112][640]          143360
#define OFF_BDP      2616320ULL    // f32  [112] pad           512
#define OFF_MASK     2616832ULL    // f32  [65536]             262144
#define OFF_HSTATE   2878976ULL    // bf16 [8][2][32][5][64]   327680
#define OFF_TAGS     3206656ULL    // u32  [8][5] spaced x32   5120
#define OFF_XBF      3211776ULL    // bf16 [65536][320]        41943040
#define OFF_HALL     45154816ULL   // bf16 [65536][600]        78643200
#define WS_NEED      123798016ULL  // ~118 MB (r3-proven size)

// ---------------------------------------------------------------------------
__global__ __launch_bounds__(256) void k_sentinel(float* __restrict__ out,
                                                  float code, int n) {
  int i = blockIdx.x * 256 + threadIdx.x;
  if (i < n) out[i] = code;
}

// ---------------------------------------------------------------------------
// k_prep: weight repack.
// WT fragment-major: per (d,cc) 61440 elems: frag f=nt*10+kt (120), lane ll
//   (64), e (8). nt -> m=nt/3,g=nt%3, jl=m*16+(ll&15); k=kt*32+(ll>>4)*8+e.
//   value = W[k*900 + g*300 + cc*60 + jl] if k<300 && jl<60 else 0.
// UT col-major [192 cols][320 K slab-padded]: col c: tile=c/16, m=tile/3,
//   g=tile%3, jl=m*16+c%16; K: slab s=k/64, jj=k%64 -> row s*60+jj (jj<60).
// ---------------------------------------------------------------------------
__global__ __launch_bounds__(256) void k_prep(
    const float* __restrict__ Wf, const float* __restrict__ Uf,
    const float* __restrict__ bfp, const float* __restrict__ Wb,
    const float* __restrict__ Ub, const float* __restrict__ bbp,
    const float* __restrict__ Wd, const float* __restrict__ bd,
    u16* __restrict__ WT, u16* __restrict__ UT,
    float* __restrict__ BX, float* __restrict__ BH,
    u16* __restrict__ WdT, float* __restrict__ bdp)
{
  const long long NWU = 2LL * 5 * 192 * 320;  // 614400
  const long long TOTAL = NWU * 2 + 1920 * 2 + 71680 + 112;
  for (long long i = (long long)blockIdx.x * 256 + threadIdx.x; i < TOTAL;
       i += 2048LL * 256) {
    long long r = i;
    if (r < NWU) {  // WT (fragment-major)
      int d = (int)(r / 307200); int q = (int)(r % 307200);
      int cc = q / 61440; int q2 = q % 61440;
      int f = q2 / 512; int ll = (q2 % 512) / 8; int e = q2 % 8;
      int nt = f / 10, kt = f % 10;
      int m = nt / 3, g = nt % 3;
      int jl = m * 16 + (ll & 15);
      int k = kt * 32 + ((ll >> 4) << 3) + e;
      float v = 0.f;
      if (k < 300 && jl < 60) {
        const float* W = d ? Wb : Wf;
        v = W[k * 900 + g * 300 + cc * 60 + jl];
      }
      WT[r] = f2bf(v);
      continue;
    }
    r -= NWU;
    if (r < NWU) {  // UT (col-major, slab-padded K)
      int d = (int)(r / 307200); int q = (int)(r % 307200);
      int c = q / 320, k = q % 320;
      int cc = c / 192, ccol = c % 192;
      int tile = ccol / 16, ii = ccol % 16;
      int m = tile / 3, g = tile % 3, jl = m * 16 + ii;
      int s = k / 64, jj = k % 64;
      float v = 0.f;
      if (jj < 60 && jl < 60) {
        const float* U = d ? Ub : Uf;
        v = U[(s * 60 + jj) * 900 + g * 300 + cc * 60 + jl];
      }
      UT[r] = f2bf(v);
      continue;
    }
    r -= NWU;
    if (r < 1920 * 2) {  // BX then BH
      int which = (int)(r / 1920); int rr = (int)(r % 1920);
      int d = rr / 960; int c = rr % 960;
      int cc = c / 192, ccol = c % 192;
      int tile = ccol / 16, ii = ccol % 16;
      int m = tile / 3, g = tile % 3, jl = m * 16 + ii;
      float v = 0.f;
      if (jl < 60) {
        const float* B = d ? bbp : bfp;
        int col = g * 300 + cc * 60 + jl;
        if (which == 0) v = B[col] + (g < 2 ? B[900 + col] : 0.f);
        else            v = (g == 2) ? B[900 + col] : 0.f;
      }
      if (which == 0) BX[rr] = v; else BH[rr] = v;
      continue;
    }
    r -= 1920 * 2;
    if (r < 71680) {  // WdT [112][640]
      int n = (int)(r / 640); int k = (int)(r % 640);
      float v = (n < 100 && k < 600) ? Wd[k * 100 + n] : 0.f;
      WdT[r] = f2bf(v);
      continue;
    }
    r -= 71680;
    if (r < 112) bdp[r] = (r < 100) ? bd[r] : 0.f;
  }
}

// ---------------------------------------------------------------------------
// k_xbf: x -> bf16 (K-padded 320) + mask. One wave per (b,t) row.
// ---------------------------------------------------------------------------
__global__ __launch_bounds__(256) void k_xbf(const float* __restrict__ x,
                                             u16* __restrict__ xbf,
                                             float* __restrict__ mask)
{
  int row = blockIdx.x * 4 + (threadIdx.x >> 6);
  int l = threadIdx.x & 63;
  const float* xr = x + (size_t)row * 300;
  u16* xo = xbf + (size_t)row * 320;
  int p = 0;
#pragma unroll
  for (int c = 0; c < 5; ++c) {
    int k = l + c * 64;
    float v = (k < 300) ? xr[k] : 0.f;
    p |= (v != 0.f);
    xo[k] = f2bf(v);
  }
  unsigned long long b = __ballot(p);
  if (l == 0) mask[row] = (b != 0ULL) ? 1.f : 0.f;
}

// ---------------------------------------------------------------------------
// k_scan
// LDS: Ufrag 122880 | xgS [32][204] f32 26112 | hOwn [32][72] u16 4608
//      = 153600 B
// ---------------------------------------------------------------------------
__global__ __launch_bounds__(256, 1) void k_scan(
    const u16* __restrict__ UTg, const u16* __restrict__ WTg,
    const float* __restrict__ BX, const float* __restrict__ BH,
    const u16* __restrict__ xbf, const float* __restrict__ mask,
    u16* __restrict__ h_state, u16* __restrict__ h_all, u32* __restrict__ tags)
{
  extern __shared__ char smem[];
  u16*   Ufrag = (u16*)smem;                 // 122880 B (120 frags x 1024 B)
  float* xgS   = (float*)(smem + 122880);    // 26112 B  [32][204]
  u16*   hOwn  = (u16*)(smem + 148992);      // 4608 B   [32][72]

  const int tid = threadIdx.x;
  const int l = tid & 63;
  const int w = tid >> 6;
  const bool isrec = (w < 2);
  const int rt = isrec ? w : (w - 2);
  const int lc15 = l & 15, lq = l >> 4;
  const int row_loc = rt * 16 + lc15;        // h-row / x-row within 32

  const int gb = blockIdx.x & 7;             // group = d*4+bc
  const int cc = blockIdx.x >> 3;            // col-chunk 0..4
  const int d = gb >> 2, bc = gb & 3;

  const u16* UT = UTg + (size_t)(d * 5 + cc) * 192 * 320;
  const u16* wb = WTg + (size_t)(d * 5 + cc) * 61440;  // fragment-major

  // ---- stage U fragments (once): frag f = nt*10+kt, lane ll ----
  for (int u = tid; u < 7680; u += 256) {
    int f = u >> 6, ll = u & 63;
    int col = (f / 10) * 16 + (ll & 15);
    int k = (f % 10) * 32 + ((ll >> 4) << 3);
    *(uint4*)(Ufrag + (size_t)u * 8) = *(const uint4*)(UT + (size_t)col * 320 + k);
  }
  for (int u = tid; u < 1152; u += 256) ((u32*)hOwn)[u] = 0;

  // persistent per-lane constants
  f32x4 bx[12]; f32x4 brh[4];
  float hold[4][4];
  if (isrec) {
#pragma unroll
    for (int m = 0; m < 4; ++m)
      brh[m] = *(const f32x4*)(BH + d * 960 + cc * 192 + (3 * m + 2) * 16 + lq * 4);
#pragma unroll
    for (int m = 0; m < 4; ++m)
#pragma unroll
      for (int e = 0; e < 4; ++e) hold[m][e] = 0.f;
  } else {
#pragma unroll
    for (int nt = 0; nt < 12; ++nt)
      bx[nt] = *(const f32x4*)(BX + d * 960 + cc * 192 + nt * 16 + lq * 4);
  }

  const int growb = bc * 32 + row_loc;       // global batch row
  u32* tg = tags + gb * 5 * 32;              // tags spaced 128 B

  __syncthreads();

  for (int t = 0; t < 512; ++t) {
    const int t_eff = d ? (511 - t) : t;
    const size_t ridx = (size_t)growb * 512 + t_eff;

    f32x4 racc[12];
    float mk = 1.f;

    if (!isrec) {
      // ================= x waves: xg(t) = x @ W + bx =================
      short8 xF[10];
      const u16* xr = xbf + ridx * 320 + (lq << 3);
#pragma unroll
      for (int kt = 0; kt < 10; ++kt) xF[kt] = *(const short8*)(xr + kt * 32);
#pragma unroll
      for (int nt = 0; nt < 12; ++nt) { f32x4 z = {0.f, 0.f, 0.f, 0.f}; racc[nt] = z; }
#pragma unroll
      for (int kt = 0; kt < 10; ++kt) {
#pragma unroll
        for (int nt = 0; nt < 12; ++nt) {
          // fragment-major: 1 KB contiguous per instruction (coalesced L2 hit)
          short8 wf = *(const short8*)(wb + ((size_t)((nt * 10 + kt) * 64 + l)) * 8);
          racc[nt] = MFMA16(wf, xF[kt], racc[nt]);
        }
      }
#pragma unroll
      for (int nt = 0; nt < 12; ++nt) {
        f32x4 v = racc[nt] + bx[nt];
        *(f32x4*)(xgS + row_loc * 204 + nt * 16 + lq * 4) = v;
      }
    } else {
      // ================= rec waves: rec(t) = h(t) @ U =================
      mk = mask[ridx];
      if (t > 0) {
        u32 need = (u32)t;
        for (;;) {
          u32 mn = 0xffffffffu;
#pragma unroll
          for (int s = 0; s < 5; ++s) {
            if (s != cc) {
              u32 v = __hip_atomic_load(tg + s * 32, __ATOMIC_RELAXED,
                                        __HIP_MEMORY_SCOPE_AGENT);
              mn = v < mn ? v : mn;
            }
          }
          if (mn >= need) break;
          __builtin_amdgcn_s_sleep(1);
        }
        // one acquire orders the slab loads below after the tag observation
        (void)__hip_atomic_load(tg + (((cc + 1) % 5)) * 32, __ATOMIC_ACQUIRE,
                                __HIP_MEMORY_SCOPE_AGENT);
        asm volatile("" ::: "memory");  // keep data loads below the poll
      }
      // B-fragments: h[row_loc][k] ; own slab via LDS, peers via agent u64
      short8 hf[10];
      {
        const int par = t & 1;
        const u64* hb = (const u64*)(h_state +
            (((size_t)(gb * 2 + par) * 32 + row_loc) * 5) * 64);
#pragma unroll
        for (int s = 0; s < 5; ++s) {
          if (s == cc) continue;
#pragma unroll
          for (int kt2 = 0; kt2 < 2; ++kt2) {
            const u64* p = hb + s * 16 + kt2 * 8 + lq * 2;
            union { u64 q[2]; short8 v; } uu;
            uu.q[0] = __hip_atomic_load(p, __ATOMIC_RELAXED, __HIP_MEMORY_SCOPE_AGENT);
            uu.q[1] = __hip_atomic_load(p + 1, __ATOMIC_RELAXED, __HIP_MEMORY_SCOPE_AGENT);
            hf[s * 2 + kt2] = uu.v;
          }
        }
#pragma unroll
        for (int kt2 = 0; kt2 < 2; ++kt2)
          hf[cc * 2 + kt2] =
              *(const short8*)(hOwn + row_loc * 72 + kt2 * 32 + (lq << 3));
      }
#pragma unroll
      for (int nt = 0; nt < 12; ++nt) { f32x4 z = {0.f, 0.f, 0.f, 0.f}; racc[nt] = z; }
#pragma unroll
      for (int kt = 0; kt < 10; ++kt) {
#pragma unroll
        for (int nt = 0; nt < 12; ++nt) {
          short8 uf = *(const short8*)(Ufrag + ((size_t)(nt * 10 + kt) * 64 + l) * 8);
          racc[nt] = MFMA16(uf, hf[kt], racc[nt]);
        }
      }
    }

    __syncthreads();  // xgS(t) ready; rec acc in regs

    if (isrec) {
      const float* xgr = xgS + row_loc * 204;
      const bool msk = (mk != 0.f);
#pragma unroll
      for (int m = 0; m < 4; ++m) {
        f32x4 xzv = *(const f32x4*)(xgr + (3 * m) * 16 + lq * 4);
        f32x4 xrv = *(const f32x4*)(xgr + (3 * m + 1) * 16 + lq * 4);
        f32x4 xhv = *(const f32x4*)(xgr + (3 * m + 2) * 16 + lq * 4);
        u16 hb16[4];
#pragma unroll
        for (int e = 0; e < 4; ++e) {
          float z = sigm(xzv[e] + racc[3 * m][e]);
          float r = sigm(xrv[e] + racc[3 * m + 1][e]);
          float hh = tanhx(xhv[e] + r * (racc[3 * m + 2][e] + brh[m][e]));
          float hn = z * hold[m][e] + (1.f - z) * hh;
          hn = msk ? hn : hold[m][e];
          hold[m][e] = hn;
          hb16[e] = f2bf(hn);
        }
        if (m < 3 || lq < 3) {   // j0..j0+3 < 60
          int j0 = m * 16 + lq * 4;
          u32 lo = (u32)hb16[0] | ((u32)hb16[1] << 16);
          u32 hi = (u32)hb16[2] | ((u32)hb16[3] << 16);
          u64 pk = (u64)lo | ((u64)hi << 32);
          // device-coherent slab store for peers
          u64* hp = (u64*)(h_state +
              ((((size_t)(gb * 2 + ((t + 1) & 1)) * 32 + row_loc) * 5 + cc) * 64 + j0));
          __hip_atomic_store(hp, pk, __ATOMIC_RELAXED, __HIP_MEMORY_SCOPE_AGENT);
          // output h (read by k_dense after kernel end)
          *(u64*)(h_all + ridx * 600 + d * 300 + cc * 60 + j0) = pk;
          // own slab for next step
          *(u64*)(hOwn + row_loc * 72 + j0) = pk;
        }
      }
    }

    __syncthreads();  // drains all stores (vmcnt 0 per wave) before tag
    if (tid == 0)
      __hip_atomic_store(tg + cc * 32, (u32)(t + 1), __ATOMIC_RELEASE,
                         __HIP_MEMORY_SCOPE_AGENT);
  }
}

// ---------------------------------------------------------------------------
// k_dense: out = tanh(h_all @ Wd + bd). M=64 tile, static LDS 22.5 KB.
// ---------------------------------------------------------------------------
__global__ __launch_bounds__(256) void k_dense(
    const u16* __restrict__ h_all, const u16* __restrict__ WdT,
    const float* __restrict__ bdp, float* __restrict__ out)
{
  __shared__ u16 Bf[7 * 2 * 64 * 8];  // 14336 B
  __shared__ char A[8192];
  const int tid = threadIdx.x;
  const int l = tid & 63;
  const int w = tid >> 6;
  const int lc15 = l & 15, lq = l >> 4;
  const int mblk = blockIdx.x;

  f32x4 acc[7];
#pragma unroll
  for (int i = 0; i < 7; ++i) { f32x4 z = {0.f, 0.f, 0.f, 0.f}; acc[i] = z; }

  for (int kc = 0; kc < 10; ++kc) {
    for (int u = tid; u < 512; u += 256) {
      int row = u >> 3, oct = u & 7;
      int k0 = kc * 64 + oct * 8;
      uint4 v = {0u, 0u, 0u, 0u};
      if (k0 <= 592)
        v = *(const uint4*)(h_all + (size_t)(mblk * 64 + row) * 600 + k0);
      *(uint4*)(A + row * 128 + ((oct * 16) ^ ((row & 7) << 4))) = v;
    }
    for (int u = tid; u < 896; u += 256) {
      int idx = u >> 6, ll = u & 63;
      int nt = idx >> 1, ktp = idx & 1;
      int kt = kc * 2 + ktp;
      uint4 v = {0u, 0u, 0u, 0u};
      if (kt < 19) {
        int col = nt * 16 + (ll & 15);
        int k = kt * 32 + ((ll >> 4) << 3);
        v = *(const uint4*)(WdT + (size_t)col * 640 + k);
      }
      *(uint4*)(Bf + (size_t)u * 8) = v;
    }
    __syncthreads();
    const int r = w * 16 + lc15;
    const int swA = (r & 7) << 4;
#pragma unroll
    for (int ktp = 0; ktp < 2; ++ktp) {
      if (kc * 2 + ktp < 19) {
        short8 aF = *(const short8*)(A + r * 128 + ((ktp * 64 + (lq << 4)) ^ swA));
#pragma unroll
        for (int nt = 0; nt < 7; ++nt) {
          short8 bF = *(const short8*)(Bf + ((size_t)((nt * 2 + ktp) * 64 + l)) * 8);
          acc[nt] = MFMA16(aF, bF, acc[nt]);
        }
      }
    }
    __syncthreads();
  }
#pragma unroll
  for (int nt = 0; nt < 7; ++nt) {
    int col = nt * 16 + lc15;
    if (col < 100) {
      float bb = bdp[col];
#pragma unroll
      for (int e = 0; e < 4; ++e) {
        int row = w * 16 + lq * 4 + e;
        out[(size_t)(mblk * 64 + row) * 100 + col] = tanhx(acc[nt][e] + bb);
      }
    }
  }
}

// ---------------------------------------------------------------------------
extern "C" void kernel_launch(void* const* d_in, const int* in_sizes, int n_in,
                              void* d_out, int out_size, void* d_ws, size_t ws_size,
                              hipStream_t stream)
{
  (void)in_sizes; (void)n_in;
  const float* x  = (const float*)d_in[0];
  const float* Wf = (const float*)d_in[1];
  const float* Uf = (const float*)d_in[2];
  const float* bf = (const float*)d_in[3];
  const float* Wb = (const float*)d_in[4];
  const float* Ub = (const float*)d_in[5];
  const float* bb = (const float*)d_in[6];
  const float* Wd = (const float*)d_in[7];
  const float* bd = (const float*)d_in[8];
  float* out = (float*)d_out;
  char* ws = (char*)d_ws;

  hipError_t e1 = hipFuncSetAttribute((const void*)k_scan,
      hipFuncAttributeMaxDynamicSharedMemorySize, 153600);

  if (ws_size < WS_NEED || e1 != hipSuccess) {
    float code = (float)(ws_size >> 20) + (e1 != hipSuccess ? 100000.f : 0.f);
    int n = out_size;
    hipLaunchKernelGGL(k_sentinel, dim3((n + 255) / 256), dim3(256), 0, stream,
                       out, code, n);
    return;
  }

  u16*   WT      = (u16*)(ws + OFF_WT);
  u16*   UT      = (u16*)(ws + OFF_UT);
  float* BX      = (float*)(ws + OFF_BX);
  float* BH      = (float*)(ws + OFF_BH);
  u16*   WdT     = (u16*)(ws + OFF_WDT);
  float* bdp     = (float*)(ws + OFF_BDP);
  float* mask    = (float*)(ws + OFF_MASK);
  u16*   h_state = (u16*)(ws + OFF_HSTATE);
  u32*   tags    = (u32*)(ws + OFF_TAGS);
  u16*   xbf     = (u16*)(ws + OFF_XBF);
  u16*   h_all   = (u16*)(ws + OFF_HALL);

  // zero h_state + tags (contiguous)
  hipMemsetAsync(ws + OFF_HSTATE, 0, 327680 + 5120, stream);

  hipLaunchKernelGGL(k_prep, dim3(2048), dim3(256), 0, stream,
                     Wf, Uf, bf, Wb, Ub, bb, Wd, bd, WT, UT, BX, BH, WdT, bdp);
  hipLaunchKernelGGL(k_xbf, dim3(16384), dim3(256), 0, stream, x, xbf, mask);
  hipLaunchKernelGGL(k_scan, dim3(40), dim3(256), 153600, stream,
                     UT, WT, BX, BH, xbf, mask, h_state, h_all, tags);
  hipLaunchKernelGGL(k_dense, dim3(1024), dim3(256), 0, stream,
                     h_all, WdT, bdp, out);
}